// Round 8
// baseline (317.164 us; speedup 1.0000x reference)
//
#include <hip/hip_runtime.h>

static constexpr int BATCH = 16;
static constexpr int NNODE = 4096;
static constexpr int NEDGE = 65536;            // 1 << 16
static constexpr int ROWS  = BATCH * NNODE;    // 65536
static constexpr int CAP   = 2432;             // compacted slots/batch (76*32)
static constexpr int PM    = BATCH * CAP;
static constexpr int DCAP  = 64;               // per-node edge-bucket capacity

typedef _Float16 half8  __attribute__((ext_vector_type(8)));
typedef _Float16 half4v __attribute__((ext_vector_type(4)));
typedef _Float16 half2v __attribute__((ext_vector_type(2)));
typedef float    f32x4  __attribute__((ext_vector_type(4)));
typedef float    f32x2  __attribute__((ext_vector_type(2)));

// ---------------- build: bucket fill + W cast + compaction (one dispatch) ---
__global__ __launch_bounds__(256) void build_kernel(
    const int* __restrict__ ei, const float* __restrict__ ew,
    const int* __restrict__ mask,
    const float* __restrict__ W1, const float* __restrict__ W2,
    const float* __restrict__ W3,
    int* __restrict__ cursor, unsigned int* __restrict__ bkt,
    _Float16* __restrict__ Wt1, _Float16* __restrict__ Wt2,
    _Float16* __restrict__ Wt3,
    int* __restrict__ vlist, int* __restrict__ validN)
{
    __shared__ int sums[256];
    const int blk = blockIdx.x;
    const int t   = threadIdx.x;

    if (blk < 4096) {
        // bkt entry = (fp16bits(w) << 16) | raw_u  (u < 4096 fits 12 bits)
        const int idx = blk * 256 + t;
        const int b = idx >> 16;
        const int e = idx & (NEDGE - 1);
        const int* eib = ei + (size_t)b * 2 * NEDGE;
        const int u = eib[e];
        const int v = eib[NEDGE + e];
        const int mrow = b * NNODE;
        if (mask[mrow + u] != 0 && mask[mrow + v] != 0) {
            const _Float16 w = (_Float16)ew[(size_t)b * NEDGE + e];
            const unsigned short wb = __builtin_bit_cast(unsigned short, w);
            const int pos = atomicAdd(&cursor[mrow + v], 1);
            if (pos < DCAP)
                bkt[(size_t)(mrow + v) * DCAP + pos] = ((unsigned)wb << 16) | (unsigned)u;
        }
    } else if (blk < 4608) {
        const int i = (blk - 4096) * 256 + t;      // [0, 131072)
        if (i < 32768) {
            int k = i >> 8, n = i & 255;
            Wt1[n * 128 + k] = (_Float16)W1[i];
        } else if (i < 98304) {
            int j = i - 32768;
            int k = j >> 8, n = j & 255;
            Wt2[n * 256 + k] = (_Float16)W2[j];
        } else {
            int j = i - 98304;
            int k = j >> 7, n = j & 127;
            Wt3[n * 256 + k] = (_Float16)W3[j];
        }
    } else {
        // per-batch node compaction
        const int b = blk - 4608;
        const int* mb = mask + b * NNODE;
        for (int i = t; i < CAP; i += 256) vlist[b * CAP + i] = 0;

        int loc[16]; int s = 0;
        #pragma unroll
        for (int i = 0; i < 16; ++i) { loc[i] = (mb[t * 16 + i] != 0); s += loc[i]; }
        sums[t] = s;
        __syncthreads();
        for (int off = 1; off < 256; off <<= 1) {
            int v = (t >= off) ? sums[t - off] : 0;
            __syncthreads();
            sums[t] += v;
            __syncthreads();
        }
        int run = (t == 0) ? 0 : sums[t - 1];
        #pragma unroll
        for (int i = 0; i < 16; ++i) {
            const int n = t * 16 + i;
            if (loc[i]) {
                if (run < CAP) vlist[b * CAP + run] = n;
                ++run;
            }
        }
        if (t == 255) validN[b] = run;
    }
}

// ---- aggregation load/FMA macros (ping-pong prefetch; static buffer names) --
#define G1_LOAD(T0, WJ, XV)                                                    \
    {   _Pragma("unroll")                                                      \
        for (int r_ = 0; r_ < 8; ++r_) {                                       \
            _Pragma("unroll")                                                  \
            for (int k_ = 0; k_ < 2; ++k_) {                                   \
                const unsigned p_ = s_bk[rbase + r_][(T0) + k_];               \
                const unsigned u_ = p_ & 0xFFFu;                               \
                const bool ok_ = ((T0) + k_) < dg[r_];                         \
                WJ[r_][k_] = ok_ ? (float)__builtin_bit_cast(_Float16,         \
                                   (unsigned short)(p_ >> 16)) : 0.0f;         \
                XV[r_][k_] = *(const float2*)(Xb + (size_t)u_ * 128);          \
            }                                                                  \
        }                                                                      \
    }
#define G1_FMA(WJ, XV)                                                         \
    {   _Pragma("unroll")                                                      \
        for (int r_ = 0; r_ < 8; ++r_) {                                       \
            _Pragma("unroll")                                                  \
            for (int k_ = 0; k_ < 2; ++k_) {                                   \
                acc8[r_][0] += WJ[r_][k_] * XV[r_][k_].x;                      \
                acc8[r_][1] += WJ[r_][k_] * XV[r_][k_].y;                      \
            }                                                                  \
        }                                                                      \
    }
#define G23_LOAD(T0, WJ, HV)                                                   \
    {   _Pragma("unroll")                                                      \
        for (int r_ = 0; r_ < 8; ++r_) {                                       \
            _Pragma("unroll")                                                  \
            for (int k_ = 0; k_ < 2; ++k_) {                                   \
                const unsigned p_ = s_bk[rbase + r_][(T0) + k_];               \
                const bool ok_ = ((T0) + k_) < dg[r_];                         \
                const unsigned u_ = ok_ ? (p_ & 0xFFFu) : vsafe;               \
                WJ[r_][k_] = ok_ ? (float)__builtin_bit_cast(_Float16,         \
                                   (unsigned short)(p_ >> 16)) : 0.0f;         \
                HV[r_][k_] = *(const half4v*)(Ab + (size_t)u_ * 256);          \
            }                                                                  \
        }                                                                      \
    }
#define G23_FMA(WJ, HV)                                                        \
    {   _Pragma("unroll")                                                      \
        for (int r_ = 0; r_ < 8; ++r_) {                                       \
            _Pragma("unroll")                                                  \
            for (int k_ = 0; k_ < 2; ++k_) {                                   \
                acc8[r_][0] += WJ[r_][k_] * (float)HV[r_][k_][0];              \
                acc8[r_][1] += WJ[r_][k_] * (float)HV[r_][k_][1];              \
                acc8[r_][2] += WJ[r_][k_] * (float)HV[r_][k_][2];              \
                acc8[r_][3] += WJ[r_][k_] * (float)HV[r_][k_][3];              \
            }                                                                  \
        }                                                                      \
    }

// ---------------- fused layer 1: aggregate(f32 x) -> W1 -> relu+b1 ----------
// Aggregation: edge-major chunks of 2 x 8 rows, explicitly double-buffered —
// chunk t0+2's 16 loads are ISSUED before chunk t0's FMAs consume buffer A,
// so the compiler must keep 16 loads in flight (round-7 post-mortem: without
// named buffers it allocated 52 VGPRs and serialized the gathers).
__global__ __launch_bounds__(256, 3) void fused_g1(
    const unsigned int* __restrict__ bkt, const int* __restrict__ cursor,
    const float* __restrict__ X,        // [ROWS, 128] f32 (raw input, finite)
    const int* __restrict__ vlist, const int* __restrict__ validN,
    const _Float16* __restrict__ Wt,    // [256, 128]
    const float* __restrict__ bias,     // b1 [256]
    _Float16* __restrict__ Ac)          // [ROWS, 256] full layout
{
    constexpr int K = 128;
    constexpr int NPAN = 4;
    constexpr int PSTR = 1032;          // padded panel stride (halfs)
    constexpr int NW = 64, NI = 4, RST = 72;
    constexpr int NCH = CAP / 32;       // 76
    constexpr int ASZ = (NPAN * PSTR) > (4 * 16 * RST) ? (NPAN * PSTR) : (4 * 16 * RST);
    __shared__ _Float16 A16[ASZ];
    __shared__ int s_v[32], s_deg[32];
    __shared__ unsigned s_bk[32][16];

    const int tid  = threadIdx.x;
    const int lane = tid & 63;
    const int wave = tid >> 6;
    const int quad = lane >> 4;
    const int l15  = lane & 15;

    const int xcd  = blockIdx.x & 7;
    const int j    = blockIdx.x >> 3;          // [0, 2*NCH)
    const int batch = 2 * xcd + (j >= NCH);
    const int tile  = (j >= NCH) ? j - NCH : j;
    const int vN   = validN[batch];
    if (tile * 32 >= vN) return;
    const int mrow = batch * NNODE;

    // ---- prologue: stage slot metadata + first-16 bucket entries ----
    if (tid < 32) {
        const int slot = tile * 32 + tid;
        int v = 0, dgv = 0;
        if (slot < vN) {
            v = vlist[batch * CAP + slot];
            dgv = cursor[mrow + v];
            dgv = dgv > DCAP ? DCAP : dgv;
        }
        s_v[tid] = v; s_deg[tid] = dgv;
    }
    __syncthreads();
    if (tid < 128) {
        const int r = tid >> 2, part = tid & 3;
        const uint4 q = *(const uint4*)&bkt[(size_t)(mrow + s_v[r]) * DCAP + part * 4];
        *(uint4*)&s_bk[r][part * 4] = q;
    }
    __syncthreads();

    // ---- aggregation: ping-pong prefetch over edge chunks ----
    const int rbase = wave * 8;
    int dg[8];
    #pragma unroll
    for (int r = 0; r < 8; ++r) dg[r] = s_deg[rbase + r];
    int mdg = 0;
    #pragma unroll
    for (int r = 0; r < 8; ++r) mdg = dg[r] > mdg ? dg[r] : mdg;
    const int nmain = mdg < 16 ? mdg : 16;     // wave-uniform

    const float* Xb = X + (size_t)mrow * 128 + lane * 2;
    f32x2 acc8[8];
    #pragma unroll
    for (int r = 0; r < 8; ++r) acc8[r] = (f32x2)0.0f;

    if (nmain > 0) {
        float  wjA[8][2], wjB[8][2];
        float2 xvA[8][2], xvB[8][2];
        G1_LOAD(0, wjA, xvA);
        for (int t0 = 0; t0 < nmain; t0 += 4) {
            const bool hasB = (t0 + 2) < nmain;          // wave-uniform
            if (hasB) G1_LOAD(t0 + 2, wjB, xvB);
            G1_FMA(wjA, xvA);
            if (hasB) {
                if (t0 + 4 < nmain) G1_LOAD(t0 + 4, wjA, xvA);
                G1_FMA(wjB, xvB);
            }
        }
    }
    if (mdg > 16) {                              // rare tail
        #pragma unroll 1
        for (int r = 0; r < 8; ++r) {
            const unsigned* bk2 = bkt + (size_t)(mrow + s_v[rbase + r]) * DCAP;
            #pragma unroll 1
            for (int i = 16; i < dg[r]; ++i) {
                const unsigned p = bk2[i];
                const float w = (float)__builtin_bit_cast(_Float16, (unsigned short)(p >> 16));
                const float2 x2 = *(const float2*)(Xb + (size_t)(p & 0xFFFu) * 128);
                acc8[r][0] += w * x2.x; acc8[r][1] += w * x2.y;
            }
        }
    }
    #pragma unroll
    for (int r = 0; r < 8; ++r) {
        half2v o = {(_Float16)acc8[r][0], (_Float16)acc8[r][1]};
        *(half2v*)&A16[(lane >> 4) * PSTR + (rbase + r) * 32 + ((lane * 2) & 31)] = o;
    }
    __syncthreads();

    // ---- GEMM W1 (M=32: mi 2) ----
    f32x4 acc[2][NI];
    #pragma unroll
    for (int mi = 0; mi < 2; ++mi)
        #pragma unroll
        for (int ni = 0; ni < NI; ++ni) acc[mi][ni] = (f32x4)0.0f;

    const _Float16* ap = A16 + l15 * 32 + quad * 8;
    const _Float16* wp = Wt + (size_t)(wave * NW + l15) * K + quad * 8;

    #pragma unroll
    for (int pp = 0; pp < NPAN; ++pp) {
        half8 af[2], bf[NI];
        #pragma unroll
        for (int mi = 0; mi < 2; ++mi)
            af[mi] = *(const half8*)(ap + pp * PSTR + mi * 16 * 32);
        #pragma unroll
        for (int ni = 0; ni < NI; ++ni)
            bf[ni] = *(const half8*)(wp + (size_t)ni * 16 * K + pp * 32);
        #pragma unroll
        for (int mi = 0; mi < 2; ++mi)
            #pragma unroll
            for (int ni = 0; ni < NI; ++ni)
                acc[mi][ni] = __builtin_amdgcn_mfma_f32_16x16x32_f16(
                    bf[ni], af[mi], acc[mi][ni], 0, 0, 0);   // swapped
    }
    __syncthreads();   // A16 free for store restage

    // ---- epilogue: relu(.+b1), scatter rows via s_v ----
    _Float16* stg = A16 + wave * 16 * RST;
    const int rr = lane >> 2;
    const int c0 = lane & 3;
    #pragma unroll
    for (int mi = 0; mi < 2; ++mi) {
        #pragma unroll
        for (int ni = 0; ni < NI; ++ni) {
            f32x4 v = acc[mi][ni];
            const f32x4 bv = *(const f32x4*)&bias[wave * NW + ni * 16 + quad * 4];
            half4v o;
            #pragma unroll
            for (int r = 0; r < 4; ++r) o[r] = (_Float16)fmaxf(v[r] + bv[r], 0.0f);
            *(half4v*)&stg[l15 * RST + ni * 16 + quad * 4] = o;
        }
        const int slot = tile * 32 + mi * 16 + rr;
        if (slot < vN) {
            const int vs = s_v[mi * 16 + rr];
            _Float16* hp2 = &Ac[((size_t)mrow + vs) * 256 + wave * NW];
            #pragma unroll
            for (int c = 0; c < NI / 2; ++c) {
                const int ch = (c0 + 4 * c) * 8;
                half8 v = *(const half8*)&stg[rr * RST + ch];
                *(half8*)(hp2 + ch) = v;
            }
        }
    }
}

// ---------------- fused layers 2+3: aggregate(Ac) -> W2 -> relu -> W3 -------
__global__ __launch_bounds__(256, 3) void fused_g23(
    const unsigned int* __restrict__ bkt, const int* __restrict__ cursor,
    const _Float16* __restrict__ Ac,    // [ROWS, 256]
    const int* __restrict__ vlist, const int* __restrict__ validN,
    const _Float16* __restrict__ Wt2,   // [256, 256]
    const _Float16* __restrict__ Wt3,   // [128, 256]
    const float* __restrict__ b2,       // [256]
    _Float16* __restrict__ H3)          // [ROWS, 128]
{
    constexpr int K    = 256;
    constexpr int NPAN = 8;
    constexpr int PSTR = 1032;
    constexpr int NCH  = CAP / 32;      // 76
    __shared__ _Float16 A16[NPAN * PSTR];   // 16.1 KB, reused 3x
    __shared__ int s_v[32], s_deg[32];
    __shared__ unsigned s_bk[32][16];

    const int tid  = threadIdx.x;
    const int lane = tid & 63;
    const int wave = tid >> 6;
    const int quad = lane >> 4;
    const int l15  = lane & 15;

    const int xcd  = blockIdx.x & 7;
    const int j    = blockIdx.x >> 3;
    const int batch = 2 * xcd + (j >= NCH);
    const int tile  = (j >= NCH) ? j - NCH : j;
    const int vN   = validN[batch];
    if (tile * 32 >= vN) return;
    const int mrow = batch * NNODE;

    // ---- prologue: stage slot metadata + first-16 bucket entries ----
    if (tid < 32) {
        const int slot = tile * 32 + tid;
        int v = 0, dgv = 0;
        if (slot < vN) {
            v = vlist[batch * CAP + slot];
            dgv = cursor[mrow + v];
            dgv = dgv > DCAP ? DCAP : dgv;
        }
        s_v[tid] = v; s_deg[tid] = dgv;
    }
    __syncthreads();
    if (tid < 128) {
        const int r = tid >> 2, part = tid & 3;
        const uint4 q = *(const uint4*)&bkt[(size_t)(mrow + s_v[r]) * DCAP + part * 4];
        *(uint4*)&s_bk[r][part * 4] = q;
    }
    __syncthreads();

    // ---- aggregation: ping-pong prefetch over edge chunks ----
    // Invalid (masked) lanes redirect to s_v[0]'s row (g1-written, finite).
    const int rbase = wave * 8;
    const unsigned vsafe = (unsigned)s_v[0];
    int dg[8];
    #pragma unroll
    for (int r = 0; r < 8; ++r) dg[r] = s_deg[rbase + r];
    int mdg = 0;
    #pragma unroll
    for (int r = 0; r < 8; ++r) mdg = dg[r] > mdg ? dg[r] : mdg;
    const int nmain = mdg < 16 ? mdg : 16;     // wave-uniform

    const _Float16* Ab = Ac + (size_t)mrow * 256 + lane * 4;
    f32x4 acc8[8];
    #pragma unroll
    for (int r = 0; r < 8; ++r) acc8[r] = (f32x4)0.0f;

    if (nmain > 0) {
        float  wjA[8][2], wjB[8][2];
        half4v hvA[8][2], hvB[8][2];
        G23_LOAD(0, wjA, hvA);
        for (int t0 = 0; t0 < nmain; t0 += 4) {
            const bool hasB = (t0 + 2) < nmain;          // wave-uniform
            if (hasB) G23_LOAD(t0 + 2, wjB, hvB);
            G23_FMA(wjA, hvA);
            if (hasB) {
                if (t0 + 4 < nmain) G23_LOAD(t0 + 4, wjA, hvA);
                G23_FMA(wjB, hvB);
            }
        }
    }
    if (mdg > 16) {
        #pragma unroll 1
        for (int r = 0; r < 8; ++r) {
            const unsigned* bk2 = bkt + (size_t)(mrow + s_v[rbase + r]) * DCAP;
            #pragma unroll 1
            for (int i = 16; i < dg[r]; ++i) {
                const unsigned p = bk2[i];
                const float w = (float)__builtin_bit_cast(_Float16, (unsigned short)(p >> 16));
                const half4v h = *(const half4v*)(Ab + (size_t)(p & 0xFFFu) * 256);
                acc8[r][0] += w * (float)h[0]; acc8[r][1] += w * (float)h[1];
                acc8[r][2] += w * (float)h[2]; acc8[r][3] += w * (float)h[3];
            }
        }
    }
    #pragma unroll
    for (int r = 0; r < 8; ++r) {
        half4v o = {(_Float16)acc8[r][0], (_Float16)acc8[r][1],
                    (_Float16)acc8[r][2], (_Float16)acc8[r][3]};
        *(half4v*)&A16[(lane >> 3) * PSTR + (rbase + r) * 32 + ((lane * 4) & 31)] = o;
    }
    __syncthreads();

    // ---- phase 1: layer-2 matmul (M=32: mi 2; 64 cols/wave: ni 4) ----
    f32x4 acc[2][4];
    #pragma unroll
    for (int mi = 0; mi < 2; ++mi)
        #pragma unroll
        for (int ni = 0; ni < 4; ++ni) acc[mi][ni] = (f32x4)0.0f;

    const _Float16* ap = A16 + l15 * 32 + quad * 8;
    const _Float16* wp = Wt2 + (size_t)(wave * 64 + l15) * K + quad * 8;

    #pragma unroll
    for (int pp = 0; pp < NPAN; ++pp) {
        half8 af[2], bf[4];
        #pragma unroll
        for (int mi = 0; mi < 2; ++mi)
            af[mi] = *(const half8*)(ap + pp * PSTR + mi * 16 * 32);
        #pragma unroll
        for (int ni = 0; ni < 4; ++ni)
            bf[ni] = *(const half8*)(wp + (size_t)ni * 16 * K + pp * 32);
        #pragma unroll
        for (int mi = 0; mi < 2; ++mi)
            #pragma unroll
            for (int ni = 0; ni < 4; ++ni)
                acc[mi][ni] = __builtin_amdgcn_mfma_f32_16x16x32_f16(
                    bf[ni], af[mi], acc[mi][ni], 0, 0, 0);
    }
    __syncthreads();   // all waves done reading agg panels

    // ---- epilogue 1: relu(acc + b2) -> A16 panel layout ----
    #pragma unroll
    for (int mi = 0; mi < 2; ++mi) {
        const int row = mi * 16 + l15;
        #pragma unroll
        for (int ni = 0; ni < 4; ++ni) {
            const int col = wave * 64 + ni * 16 + quad * 4;
            const f32x4 bv = *(const f32x4*)&b2[col];
            f32x4 v = acc[mi][ni];
            half4v o;
            #pragma unroll
            for (int r = 0; r < 4; ++r) o[r] = (_Float16)fmaxf(v[r] + bv[r], 0.0f);
            *(half4v*)&A16[(col >> 5) * PSTR + row * 32 + (col & 31)] = o;
        }
    }
    __syncthreads();

    // ---- phase 2: layer-3 matmul from LDS (32 cols/wave: ni 2) ----
    f32x4 acc2[2][2];
    #pragma unroll
    for (int mi = 0; mi < 2; ++mi)
        #pragma unroll
        for (int ni = 0; ni < 2; ++ni) acc2[mi][ni] = (f32x4)0.0f;

    const _Float16* wp3 = Wt3 + (size_t)(wave * 32 + l15) * K + quad * 8;
    #pragma unroll
    for (int pp = 0; pp < NPAN; ++pp) {
        half8 af[2], bf[2];
        #pragma unroll
        for (int mi = 0; mi < 2; ++mi)
            af[mi] = *(const half8*)(ap + pp * PSTR + mi * 16 * 32);
        #pragma unroll
        for (int ni = 0; ni < 2; ++ni)
            bf[ni] = *(const half8*)(wp3 + (size_t)ni * 16 * K + pp * 32);
        #pragma unroll
        for (int mi = 0; mi < 2; ++mi)
            #pragma unroll
            for (int ni = 0; ni < 2; ++ni)
                acc2[mi][ni] = __builtin_amdgcn_mfma_f32_16x16x32_f16(
                    bf[ni], af[mi], acc2[mi][ni], 0, 0, 0);
    }
    __syncthreads();   // A16 free for store restage

    constexpr int RST = 40;            // 32 + 8 pad
    _Float16* stg = A16 + wave * 16 * RST;
    const int rr = lane >> 2;
    const int c0 = lane & 3;
    #pragma unroll
    for (int mi = 0; mi < 2; ++mi) {
        #pragma unroll
        for (int ni = 0; ni < 2; ++ni) {
            f32x4 v = acc2[mi][ni];
            half4v o;
            #pragma unroll
            for (int r = 0; r < 4; ++r) o[r] = (_Float16)v[r];
            *(half4v*)&stg[l15 * RST + ni * 16 + quad * 4] = o;
        }
        const int slot = tile * 32 + mi * 16 + rr;
        if (slot < vN) {
            const int vs = s_v[mi * 16 + rr];
            _Float16* hp2 = &H3[((size_t)mrow + vs) * 128 + wave * 32];
            const int ch = c0 * 8;
            half8 v = *(const half8*)&stg[rr * RST + ch];
            *(half8*)(hp2 + ch) = v;
        }
    }
}

// ---------------- final gather (1 node/wave, static XCD-affine) -------------
__global__ __launch_bounds__(256) void gather_final(
    const int* __restrict__ cursor, const unsigned int* __restrict__ bkt,
    const _Float16* __restrict__ H3,   // [ROWS, 128]
    const int* __restrict__ mask, const float* __restrict__ bias,
    float* __restrict__ OUT)           // [ROWS, 128]
{
    constexpr int NU = NNODE / 4;      // 1024 units (4 nodes) per batch
    const int tid  = threadIdx.x;
    const int lane = tid & 63;
    const int wave = tid >> 6;

    const int xcd  = blockIdx.x & 7;
    const int jj   = blockIdx.x >> 3;
    const int batch = 2 * xcd + (jj >= NU);
    const int unit  = (jj >= NU) ? jj - NU : jj;

    const int n = unit * 4 + wave;
    const int mrow = batch * NNODE + n;

    float acc[2] = {};
    if (mask[mrow] != 0) {
        int deg = cursor[mrow];
        deg = deg > DCAP ? DCAP : deg;
        const unsigned* bk = bkt + (size_t)mrow * DCAP;
        const _Float16* Hb = H3 + (size_t)batch * NNODE * 128 + lane * 2;

        for (int i = 0; i < deg; i += 8) {
            const int cnt = deg - i;
            unsigned pk[8];
            #pragma unroll
            for (int t = 0; t < 8; ++t) pk[t] = bk[i + t];
            const unsigned u0 = pk[0] & 0xFFFu;
            float wj[8]; const _Float16* hp[8];
            #pragma unroll
            for (int t = 0; t < 8; ++t) {
                const bool ok = (t < cnt);
                const unsigned u = ok ? (pk[t] & 0xFFFu) : u0;
                wj[t] = ok ? (float)__builtin_bit_cast(_Float16, (unsigned short)(pk[t] >> 16)) : 0.0f;
                hp[t] = Hb + (size_t)u * 128;
            }
            half2v hv[8];
            #pragma unroll
            for (int t = 0; t < 8; ++t) hv[t] = *(const half2v*)hp[t];
            #pragma unroll
            for (int t = 0; t < 8; ++t)
                #pragma unroll
                for (int c = 0; c < 2; ++c) acc[c] += wj[t] * (float)hv[t][c];
        }
        #pragma unroll
        for (int c = 0; c < 2; ++c)
            acc[c] = fmaxf(acc[c] + bias[lane * 2 + c], 0.0f);
    }
    f32x2 o = {acc[0], acc[1]};
    *(f32x2*)&OUT[(size_t)mrow * 128 + lane * 2] = o;
}

extern "C" void kernel_launch(void* const* d_in, const int* in_sizes, int n_in,
                              void* d_out, int out_size, void* d_ws, size_t ws_size,
                              hipStream_t stream) {
    const float* x    = (const float*)d_in[0];
    const int*   ei   = (const int*)  d_in[1];
    const float* ew   = (const float*)d_in[2];
    const int*   mask = (const int*)  d_in[3];
    const float* W1   = (const float*)d_in[4];
    const float* b1   = (const float*)d_in[5];
    const float* W2   = (const float*)d_in[6];
    const float* b2   = (const float*)d_in[7];
    const float* W3   = (const float*)d_in[8];
    const float* b3   = (const float*)d_in[9];
    float* out = (float*)d_out;

    // Workspace layout (~65 MB):
    char* ws = (char*)d_ws;
    _Float16* Ac  = (_Float16*)(ws);                       // 32 MB [ROWS,256]
    _Float16* H3  = (_Float16*)(ws + (32u << 20));         // 16 MB [ROWS,128]
    unsigned int* bkt = (unsigned int*)(ws + (48u << 20)); // 16 MB [ROWS,DCAP]
    _Float16* Wt1 = (_Float16*)(ws + (64u << 20));         // 64 KB
    _Float16* Wt2 = Wt1 + 128 * 256;                       // 128 KB
    _Float16* Wt3 = Wt2 + 256 * 256;                       // 64 KB
    int* cursor   = (int*)(Wt3 + 256 * 128);               // 256 KB (degrees)
    int* vlist    = cursor + ROWS;                         // 152 KB
    int* validN   = vlist + PM;

    const dim3 blk(256);

    // ---- 1. zero degree cursors ----
    hipMemsetAsync(cursor, 0, (size_t)ROWS * sizeof(int), stream);

    // ---- 2. build: buckets + W casts + compaction (one dispatch) ----
    build_kernel<<<4624, blk, 0, stream>>>(ei, ew, mask, W1, W2, W3,
                                           cursor, bkt, Wt1, Wt2, Wt3,
                                           vlist, validN);

    const int gemmBlocks = PM / 32;      // 1216
    const int finBlocks  = ROWS / 4;     // 16384

    // ---- 3. layer 1: aggregate f32 x + GEMM W1 + relu ----
    fused_g1<<<gemmBlocks, blk, 0, stream>>>(bkt, cursor, x, vlist, validN,
                                             Wt1, b1, Ac);

    // ---- 4. layers 2+3: aggregate + W2 + relu + W3 (LDS-resident) ----
    fused_g23<<<gemmBlocks, blk, 0, stream>>>(bkt, cursor, Ac, vlist, validN,
                                              Wt2, Wt3, b2, H3);

    // ---- 5. layer-3 aggregation + bias/relu/mask ----
    gather_final<<<finBlocks, blk, 0, stream>>>(cursor, bkt, H3, mask, b3, out);
}

// Round 9
// 208.381 us; speedup vs baseline: 1.5220x; 1.5220x over previous
//
#include <hip/hip_runtime.h>

static constexpr int BATCH = 16;
static constexpr int NNODE = 4096;
static constexpr int NEDGE = 65536;            // 1 << 16
static constexpr int ROWS  = BATCH * NNODE;    // 65536
static constexpr int CAP   = 2432;             // compacted slots/batch (38*64)
static constexpr int PM    = BATCH * CAP;
static constexpr int DCAP  = 64;               // per-node edge-bucket capacity

typedef _Float16 half8  __attribute__((ext_vector_type(8)));
typedef _Float16 half4v __attribute__((ext_vector_type(4)));
typedef _Float16 half2v __attribute__((ext_vector_type(2)));
typedef float    f32x4  __attribute__((ext_vector_type(4)));
typedef float    f32x2  __attribute__((ext_vector_type(2)));

#define GP(p) (const __attribute__((address_space(1))) void*)(p)
#define LP(p) (__attribute__((address_space(3))) void*)(p)

// ---------------- build: bucket fill + W cast + compaction (one dispatch) ---
__global__ __launch_bounds__(256) void build_kernel(
    const int* __restrict__ ei, const float* __restrict__ ew,
    const int* __restrict__ mask,
    const float* __restrict__ W1, const float* __restrict__ W2,
    const float* __restrict__ W3,
    int* __restrict__ cursor, unsigned int* __restrict__ bkt,
    _Float16* __restrict__ Wt1, _Float16* __restrict__ Wt2,
    _Float16* __restrict__ Wt3,
    int* __restrict__ vlist, int* __restrict__ validN)
{
    __shared__ int sums[256];
    const int blk = blockIdx.x;
    const int t   = threadIdx.x;

    if (blk < 4096) {
        // bkt entry = (fp16bits(w) << 16) | raw_u  (u < 4096 fits 12 bits)
        const int idx = blk * 256 + t;
        const int b = idx >> 16;
        const int e = idx & (NEDGE - 1);
        const int* eib = ei + (size_t)b * 2 * NEDGE;
        const int u = eib[e];
        const int v = eib[NEDGE + e];
        const int mrow = b * NNODE;
        if (mask[mrow + u] != 0 && mask[mrow + v] != 0) {
            const _Float16 w = (_Float16)ew[(size_t)b * NEDGE + e];
            const unsigned short wb = __builtin_bit_cast(unsigned short, w);
            const int pos = atomicAdd(&cursor[mrow + v], 1);
            if (pos < DCAP)
                bkt[(size_t)(mrow + v) * DCAP + pos] = ((unsigned)wb << 16) | (unsigned)u;
        }
    } else if (blk < 4608) {
        const int i = (blk - 4096) * 256 + t;      // [0, 131072)
        if (i < 32768) {
            int k = i >> 8, n = i & 255;
            Wt1[n * 128 + k] = (_Float16)W1[i];
        } else if (i < 98304) {
            int j = i - 32768;
            int k = j >> 8, n = j & 255;
            Wt2[n * 256 + k] = (_Float16)W2[j];
        } else {
            int j = i - 98304;
            int k = j >> 7, n = j & 127;
            Wt3[n * 256 + k] = (_Float16)W3[j];
        }
    } else {
        // per-batch node compaction
        const int b = blk - 4608;
        const int* mb = mask + b * NNODE;
        for (int i = t; i < CAP; i += 256) vlist[b * CAP + i] = 0;

        int loc[16]; int s = 0;
        #pragma unroll
        for (int i = 0; i < 16; ++i) { loc[i] = (mb[t * 16 + i] != 0); s += loc[i]; }
        sums[t] = s;
        __syncthreads();
        for (int off = 1; off < 256; off <<= 1) {
            int v = (t >= off) ? sums[t - off] : 0;
            __syncthreads();
            sums[t] += v;
            __syncthreads();
        }
        int run = (t == 0) ? 0 : sums[t - 1];
        #pragma unroll
        for (int i = 0; i < 16; ++i) {
            const int n = t * 16 + i;
            if (loc[i]) {
                if (run < CAP) vlist[b * CAP + run] = n;
                ++run;
            }
        }
        if (t == 255) validN[b] = run;
    }
}

// ---------------- standalone gathers: 1 slot/wave, TLP hides latency --------
// 38912 waves (152/CU) — per-wave load serialization is irrelevant at this
// oversubscription (round-8 post-mortem: in-GEMM gather ILP unattainable;
// gather_final at this shape has never been a top-5 dispatch).

__global__ __launch_bounds__(256) void gather_x(
    const int* __restrict__ cursor, const unsigned int* __restrict__ bkt,
    const float* __restrict__ X,       // [ROWS, 128] f32 (input)
    const int* __restrict__ vlist, const int* __restrict__ validN,
    _Float16* __restrict__ AggX)       // [PM, 128] compact
{
    constexpr int NU = CAP / 4;        // 608
    const int lane = threadIdx.x & 63;
    const int wave = threadIdx.x >> 6;
    const int xcd  = blockIdx.x & 7;
    const int jj   = blockIdx.x >> 3;
    const int batch = 2 * xcd + (jj >= NU);
    const int unit  = (jj >= NU) ? jj - NU : jj;

    const int j = unit * 4 + wave;
    if (j >= validN[batch]) return;
    const int mrow = batch * NNODE;
    const int v = vlist[batch * CAP + j];
    int deg = cursor[mrow + v];
    deg = deg > DCAP ? DCAP : deg;
    const unsigned* bk = bkt + (size_t)(mrow + v) * DCAP;
    const float* Xb = X + (size_t)mrow * 128 + lane * 2;

    float a0 = 0.0f, a1 = 0.0f;
    for (int i = 0; i < deg; i += 8) {
        const int cnt = deg - i;
        unsigned pk[8];
        #pragma unroll
        for (int t = 0; t < 8; ++t) pk[t] = bk[i + t];   // slack overread in-ws
        float wj[8]; float2 xv[8];
        #pragma unroll
        for (int t = 0; t < 8; ++t) {
            const bool ok = (t < cnt);
            const unsigned u = pk[t] & 0xFFFu;           // < 4096: in-batch
            wj[t] = ok ? (float)__builtin_bit_cast(_Float16, (unsigned short)(pk[t] >> 16)) : 0.0f;
            xv[t] = *(const float2*)(Xb + (size_t)u * 128);
        }
        #pragma unroll
        for (int t = 0; t < 8; ++t) { a0 += wj[t] * xv[t].x; a1 += wj[t] * xv[t].y; }
    }
    half2v o = {(_Float16)a0, (_Float16)a1};
    *(half2v*)&AggX[(size_t)(batch * CAP + j) * 128 + lane * 2] = o;
}

__global__ __launch_bounds__(256) void gather_agg(
    const int* __restrict__ cursor, const unsigned int* __restrict__ bkt,
    const _Float16* __restrict__ Ac,   // [ROWS, 256] full layout
    const int* __restrict__ vlist, const int* __restrict__ validN,
    _Float16* __restrict__ AggA)       // [PM, 256] compact
{
    constexpr int NU = CAP / 4;
    const int lane = threadIdx.x & 63;
    const int wave = threadIdx.x >> 6;
    const int xcd  = blockIdx.x & 7;
    const int jj   = blockIdx.x >> 3;
    const int batch = 2 * xcd + (jj >= NU);
    const int unit  = (jj >= NU) ? jj - NU : jj;

    const int j = unit * 4 + wave;
    if (j >= validN[batch]) return;
    const int mrow = batch * NNODE;
    const int v = vlist[batch * CAP + j];
    int deg = cursor[mrow + v];
    deg = deg > DCAP ? DCAP : deg;
    const unsigned* bk = bkt + (size_t)(mrow + v) * DCAP;
    const _Float16* Ab = Ac + (size_t)mrow * 256 + lane * 4;

    float a0 = 0.0f, a1 = 0.0f, a2 = 0.0f, a3 = 0.0f;
    for (int i = 0; i < deg; i += 8) {
        const int cnt = deg - i;
        unsigned pk[8];
        #pragma unroll
        for (int t = 0; t < 8; ++t) pk[t] = bk[i + t];
        float wj[8]; half4v hv[8];
        #pragma unroll
        for (int t = 0; t < 8; ++t) {
            const bool ok = (t < cnt);
            const unsigned u = pk[t] & 0xFFFu;           // valid u: Ac row written
            wj[t] = ok ? (float)__builtin_bit_cast(_Float16, (unsigned short)(pk[t] >> 16)) : 0.0f;
            hv[t] = *(const half4v*)(Ab + (size_t)u * 256);
        }
        #pragma unroll
        for (int t = 0; t < 8; ++t) {
            a0 += wj[t] * (float)hv[t][0];
            a1 += wj[t] * (float)hv[t][1];
            a2 += wj[t] * (float)hv[t][2];
            a3 += wj[t] * (float)hv[t][3];
        }
    }
    half4v o = {(_Float16)a0, (_Float16)a1, (_Float16)a2, (_Float16)a3};
    *(half4v*)&AggA[(size_t)(batch * CAP + j) * 256 + lane * 4] = o;
}

// ---------------- GEMM layer 1: AggX @ W1 -> relu+b1 -> scatter Ac ---------
// 64-row tiles, global_load_lds staging from compact AggX (linear,
// coalesced), scatter epilogue to full-layout Ac via s_v.
__global__ __launch_bounds__(256, 3) void gemm1_kernel(
    const _Float16* __restrict__ Xc,   // AggX [PM, 128] compact
    const int* __restrict__ vlist, const int* __restrict__ validN,
    const _Float16* __restrict__ Wt,   // [256, 128]
    const float* __restrict__ bias,    // b1
    _Float16* __restrict__ Ac)         // [ROWS, 256] full layout
{
    constexpr int K = 128, NW = 64, NI = 4, RST = 72;
    constexpr int NPAN = 4;
    constexpr int NCH  = CAP / 64;     // 38
    constexpr int ASZ  = (NPAN * 2048) > (4 * 16 * RST) ? (NPAN * 2048) : (4 * 16 * RST);
    __shared__ _Float16 A16[ASZ];      // 16 KB, reused for store restage
    __shared__ int s_v[64];

    const int tid  = threadIdx.x;
    const int lane = tid & 63;
    const int wave = tid >> 6;
    const int quad = lane >> 4;
    const int l15  = lane & 15;

    const int xcd  = blockIdx.x & 7;
    const int j    = blockIdx.x >> 3;          // [0, 2*NCH)
    const int batch = 2 * xcd + (j >= NCH);
    const int tile  = (j >= NCH) ? j - NCH : j;
    const int vN   = validN[batch];
    if (tile * 64 >= vN) return;
    const int mrow = batch * NNODE;
    const size_t bm = (size_t)batch * CAP + (size_t)tile * 64;

    if (tid < 64) {
        const int slot = tile * 64 + tid;
        s_v[tid] = (slot < vN) ? vlist[batch * CAP + slot] : 0;
    }
    const int srow = tid >> 2;                 // 0..63
    const int sch  = (tid & 3) * 8;
    #pragma unroll
    for (int pp = 0; pp < NPAN; ++pp)
        __builtin_amdgcn_global_load_lds(
            GP(Xc + (bm + srow) * K + pp * 32 + sch),
            LP(A16 + pp * 2048 + tid * 8), 16, 0, 0);
    __syncthreads();

    f32x4 acc[4][NI];
    #pragma unroll
    for (int mi = 0; mi < 4; ++mi)
        #pragma unroll
        for (int ni = 0; ni < NI; ++ni) acc[mi][ni] = (f32x4)0.0f;

    const _Float16* ap = A16 + l15 * 32 + quad * 8;
    const _Float16* wp = Wt + (size_t)(wave * NW + l15) * K + quad * 8;

    #pragma unroll
    for (int pp = 0; pp < NPAN; ++pp) {
        half8 af[4], bf[NI];
        #pragma unroll
        for (int mi = 0; mi < 4; ++mi)
            af[mi] = *(const half8*)(ap + pp * 2048 + mi * 16 * 32);
        #pragma unroll
        for (int ni = 0; ni < NI; ++ni)
            bf[ni] = *(const half8*)(wp + (size_t)ni * 16 * K + pp * 32);
        #pragma unroll
        for (int mi = 0; mi < 4; ++mi)
            #pragma unroll
            for (int ni = 0; ni < NI; ++ni)
                acc[mi][ni] = __builtin_amdgcn_mfma_f32_16x16x32_f16(
                    bf[ni], af[mi], acc[mi][ni], 0, 0, 0);   // swapped
    }
    __syncthreads();   // A16 free for store restage

    _Float16* stg = A16 + wave * 16 * RST;
    const int rr = lane >> 2;
    const int c0 = lane & 3;
    #pragma unroll
    for (int mi = 0; mi < 4; ++mi) {
        #pragma unroll
        for (int ni = 0; ni < NI; ++ni) {
            f32x4 v = acc[mi][ni];
            const f32x4 bv = *(const f32x4*)&bias[wave * NW + ni * 16 + quad * 4];
            half4v o;
            #pragma unroll
            for (int r = 0; r < 4; ++r) o[r] = (_Float16)fmaxf(v[r] + bv[r], 0.0f);
            *(half4v*)&stg[l15 * RST + ni * 16 + quad * 4] = o;
        }
        const int slot = tile * 64 + mi * 16 + rr;
        if (slot < vN) {
            const int vs = s_v[mi * 16 + rr];
            _Float16* hp2 = &Ac[((size_t)mrow + vs) * 256 + wave * NW];
            #pragma unroll
            for (int c = 0; c < NI / 2; ++c) {
                const int ch = (c0 + 4 * c) * 8;
                half8 v = *(const half8*)&stg[rr * RST + ch];
                *(half8*)(hp2 + ch) = v;
            }
        }
    }
}

// ---------------- GEMM layers 2+3: AggA @ W2 -> relu -> @ W3 -> scatter H3 --
__global__ __launch_bounds__(256, 3) void gemm23_kernel(
    const _Float16* __restrict__ Xc,   // AggA [PM, 256] compact
    const int* __restrict__ vlist, const int* __restrict__ validN,
    const _Float16* __restrict__ Wt2,  // [256, 256]
    const _Float16* __restrict__ Wt3,  // [128, 256]
    const float* __restrict__ b2,
    _Float16* __restrict__ H3)         // [ROWS, 128] full layout
{
    constexpr int K    = 256;
    constexpr int NPAN = 8;
    constexpr int NCH  = CAP / 64;     // 38
    __shared__ _Float16 A16[NPAN * 2048];   // 32 KB, reused 3x
    __shared__ int s_v[64];

    const int tid  = threadIdx.x;
    const int lane = tid & 63;
    const int wave = tid >> 6;
    const int quad = lane >> 4;
    const int l15  = lane & 15;

    const int xcd  = blockIdx.x & 7;
    const int j    = blockIdx.x >> 3;
    const int batch = 2 * xcd + (j >= NCH);
    const int tile  = (j >= NCH) ? j - NCH : j;
    const int vN   = validN[batch];
    if (tile * 64 >= vN) return;
    const int mrow = batch * NNODE;
    const size_t bm = (size_t)batch * CAP + (size_t)tile * 64;

    if (tid < 64) {
        const int slot = tile * 64 + tid;
        s_v[tid] = (slot < vN) ? vlist[batch * CAP + slot] : 0;
    }
    const int srow = tid >> 2;
    const int sch  = (tid & 3) * 8;
    #pragma unroll
    for (int pp = 0; pp < NPAN; ++pp)
        __builtin_amdgcn_global_load_lds(
            GP(Xc + (bm + srow) * K + pp * 32 + sch),
            LP(A16 + pp * 2048 + tid * 8), 16, 0, 0);
    __syncthreads();

    // ---- phase 1: layer-2 matmul (64 cols/wave, NI=4) ----
    f32x4 acc[4][4];
    #pragma unroll
    for (int mi = 0; mi < 4; ++mi)
        #pragma unroll
        for (int ni = 0; ni < 4; ++ni) acc[mi][ni] = (f32x4)0.0f;

    const _Float16* ap = A16 + l15 * 32 + quad * 8;
    const _Float16* wp = Wt2 + (size_t)(wave * 64 + l15) * K + quad * 8;

    #pragma unroll
    for (int pp = 0; pp < NPAN; ++pp) {
        half8 af[4], bf[4];
        #pragma unroll
        for (int mi = 0; mi < 4; ++mi)
            af[mi] = *(const half8*)(ap + pp * 2048 + mi * 16 * 32);
        #pragma unroll
        for (int ni = 0; ni < 4; ++ni)
            bf[ni] = *(const half8*)(wp + (size_t)ni * 16 * K + pp * 32);
        #pragma unroll
        for (int mi = 0; mi < 4; ++mi)
            #pragma unroll
            for (int ni = 0; ni < 4; ++ni)
                acc[mi][ni] = __builtin_amdgcn_mfma_f32_16x16x32_f16(
                    bf[ni], af[mi], acc[mi][ni], 0, 0, 0);
    }
    __syncthreads();   // all waves done reading AggA panels

    // ---- epilogue 1: relu(acc + b2) -> A16 panel layout [pp][row][32] ----
    #pragma unroll
    for (int mi = 0; mi < 4; ++mi) {
        const int row = mi * 16 + l15;
        #pragma unroll
        for (int ni = 0; ni < 4; ++ni) {
            const int col = wave * 64 + ni * 16 + quad * 4;
            const f32x4 bv = *(const f32x4*)&b2[col];
            f32x4 v = acc[mi][ni];
            half4v o;
            #pragma unroll
            for (int r = 0; r < 4; ++r) o[r] = (_Float16)fmaxf(v[r] + bv[r], 0.0f);
            *(half4v*)&A16[(col >> 5) * 2048 + row * 32 + (col & 31)] = o;
        }
    }
    __syncthreads();

    // ---- phase 2: layer-3 matmul from LDS (32 cols/wave, NI=2) ----
    f32x4 acc2[4][2];
    #pragma unroll
    for (int mi = 0; mi < 4; ++mi)
        #pragma unroll
        for (int ni = 0; ni < 2; ++ni) acc2[mi][ni] = (f32x4)0.0f;

    const _Float16* wp3 = Wt3 + (size_t)(wave * 32 + l15) * K + quad * 8;
    #pragma unroll
    for (int pp = 0; pp < NPAN; ++pp) {
        half8 af[4], bf[2];
        #pragma unroll
        for (int mi = 0; mi < 4; ++mi)
            af[mi] = *(const half8*)(ap + pp * 2048 + mi * 16 * 32);
        #pragma unroll
        for (int ni = 0; ni < 2; ++ni)
            bf[ni] = *(const half8*)(wp3 + (size_t)ni * 16 * K + pp * 32);
        #pragma unroll
        for (int mi = 0; mi < 4; ++mi)
            #pragma unroll
            for (int ni = 0; ni < 2; ++ni)
                acc2[mi][ni] = __builtin_amdgcn_mfma_f32_16x16x32_f16(
                    bf[ni], af[mi], acc2[mi][ni], 0, 0, 0);
    }
    __syncthreads();   // A16 free for store restage

    constexpr int RST = 40;            // 32 + 8 pad
    _Float16* stg = A16 + wave * 16 * RST;
    const int rr = lane >> 2;
    const int c0 = lane & 3;
    #pragma unroll
    for (int mi = 0; mi < 4; ++mi) {
        #pragma unroll
        for (int ni = 0; ni < 2; ++ni) {
            f32x4 v = acc2[mi][ni];
            half4v o;
            #pragma unroll
            for (int r = 0; r < 4; ++r) o[r] = (_Float16)v[r];
            *(half4v*)&stg[l15 * RST + ni * 16 + quad * 4] = o;
        }
        const int slot = tile * 64 + mi * 16 + rr;
        if (slot < vN) {
            const int vs = s_v[mi * 16 + rr];
            _Float16* hp2 = &H3[((size_t)mrow + vs) * 128 + wave * 32];
            const int ch = c0 * 8;
            half8 v = *(const half8*)&stg[rr * RST + ch];
            *(half8*)(hp2 + ch) = v;
        }
    }
}

// ---------------- final gather (1 node/wave, static XCD-affine) -------------
__global__ __launch_bounds__(256) void gather_final(
    const int* __restrict__ cursor, const unsigned int* __restrict__ bkt,
    const _Float16* __restrict__ H3,   // [ROWS, 128]
    const int* __restrict__ mask, const float* __restrict__ bias,
    float* __restrict__ OUT)           // [ROWS, 128]
{
    constexpr int NU = NNODE / 4;      // 1024 units (4 nodes) per batch
    const int lane = threadIdx.x & 63;
    const int wave = threadIdx.x >> 6;

    const int xcd  = blockIdx.x & 7;
    const int jj   = blockIdx.x >> 3;
    const int batch = 2 * xcd + (jj >= NU);
    const int unit  = (jj >= NU) ? jj - NU : jj;

    const int n = unit * 4 + wave;
    const int mrow = batch * NNODE + n;

    float acc[2] = {};
    if (mask[mrow] != 0) {
        int deg = cursor[mrow];
        deg = deg > DCAP ? DCAP : deg;
        const unsigned* bk = bkt + (size_t)mrow * DCAP;
        const _Float16* Hb = H3 + (size_t)batch * NNODE * 128 + lane * 2;

        for (int i = 0; i < deg; i += 8) {
            const int cnt = deg - i;
            unsigned pk[8];
            #pragma unroll
            for (int t = 0; t < 8; ++t) pk[t] = bk[i + t];
            float wj[8]; const _Float16* hp[8];
            #pragma unroll
            for (int t = 0; t < 8; ++t) {
                const bool ok = (t < cnt);
                const unsigned u = pk[t] & 0xFFFu;
                wj[t] = ok ? (float)__builtin_bit_cast(_Float16, (unsigned short)(pk[t] >> 16)) : 0.0f;
                hp[t] = Hb + (size_t)u * 128;
            }
            half2v hv[8];
            #pragma unroll
            for (int t = 0; t < 8; ++t) hv[t] = *(const half2v*)hp[t];
            #pragma unroll
            for (int t = 0; t < 8; ++t)
                #pragma unroll
                for (int c = 0; c < 2; ++c) acc[c] += wj[t] * (float)hv[t][c];
        }
        #pragma unroll
        for (int c = 0; c < 2; ++c)
            acc[c] = fmaxf(acc[c] + bias[lane * 2 + c], 0.0f);
    }
    f32x2 o = {acc[0], acc[1]};
    *(f32x2*)&OUT[(size_t)mrow * 128 + lane * 2] = o;
}

extern "C" void kernel_launch(void* const* d_in, const int* in_sizes, int n_in,
                              void* d_out, int out_size, void* d_ws, size_t ws_size,
                              hipStream_t stream) {
    const float* x    = (const float*)d_in[0];
    const int*   ei   = (const int*)  d_in[1];
    const float* ew   = (const float*)d_in[2];
    const int*   mask = (const int*)  d_in[3];
    const float* W1   = (const float*)d_in[4];
    const float* b1   = (const float*)d_in[5];
    const float* W2   = (const float*)d_in[6];
    const float* b2   = (const float*)d_in[7];
    const float* W3   = (const float*)d_in[8];
    const float* b3   = (const float*)d_in[9];
    float* out = (float*)d_out;

    // Workspace layout (~101 MB):
    char* ws = (char*)d_ws;
    _Float16* Ac   = (_Float16*)(ws);                      // 32 MB [ROWS,256] full
    _Float16* H3   = (_Float16*)(ws + (32u << 20));        // 16 MB [ROWS,128] full
    unsigned int* bkt = (unsigned int*)(ws + (48u << 20)); // 16 MB [ROWS,DCAP]
    _Float16* AggX = (_Float16*)(ws + (64u << 20));        // 10 MB [PM,128] compact
    _Float16* AggA = (_Float16*)(ws + (74u << 20));        // 20 MB [PM,256] compact
    _Float16* Wt1  = (_Float16*)(ws + (94u << 20));        // 64 KB
    _Float16* Wt2  = Wt1 + 128 * 256;                      // 128 KB
    _Float16* Wt3  = Wt2 + 256 * 256;                      // 64 KB
    int* cursor    = (int*)(Wt3 + 256 * 128);              // 256 KB (degrees)
    int* vlist     = cursor + ROWS;                        // 152 KB
    int* validN    = vlist + PM;

    const dim3 blk(256);

    // ---- 1. zero degree cursors ----
    hipMemsetAsync(cursor, 0, (size_t)ROWS * sizeof(int), stream);

    // ---- 2. build: buckets + W casts + compaction (one dispatch) ----
    build_kernel<<<4624, blk, 0, stream>>>(ei, ew, mask, W1, W2, W3,
                                           cursor, bkt, Wt1, Wt2, Wt3,
                                           vlist, validN);

    const int gemmBlocks = PM / 64;      // 608
    const int aggBlocks  = PM / 4;       // 9728
    const int finBlocks  = ROWS / 4;     // 16384

    // ---- 3. layer 1: standalone aggregation (agg-first linearity), GEMM ----
    gather_x<<<aggBlocks, blk, 0, stream>>>(cursor, bkt, x, vlist, validN, AggX);
    gemm1_kernel<<<gemmBlocks, blk, 0, stream>>>(AggX, vlist, validN, Wt1, b1, Ac);

    // ---- 4. layers 2+3: standalone aggregation, fused 2-layer GEMM ----
    gather_agg<<<aggBlocks, blk, 0, stream>>>(cursor, bkt, Ac, vlist, validN, AggA);
    gemm23_kernel<<<gemmBlocks, blk, 0, stream>>>(AggA, vlist, validN, Wt2, Wt3, b2, H3);

    // ---- 5. layer-3 aggregation + bias/relu/mask ----
    gather_final<<<finBlocks, blk, 0, stream>>>(cursor, bkt, H3, mask, b3, out);
}